// Round 11
// baseline (624.746 us; speedup 1.0000x reference)
//
#include <hip/hip_runtime.h>

// Problem constants: B=16,N=100,E=9900,M=50,F=64,H=128,K=20,D=2,T=8,S=8
#define BB 16
#define NN 100
#define EE 9900
#define MM 50
#define FF 64
#define KK 20
#define DD 2
#define ROWS (BB*EE)      // 158400 edge rows
#define HROWS (BB*MM)     // 800 hyper rows
#define BN_CNT (BB*NN)    // 1600
#define NTILE (ROWS/64)   // 2475 tiles of 64 rows
#define GEMMB 825         // gemm grid: 3 tiles/block, ~3.2 blocks/CU co-resident
#define EPSF 1e-5f
#define XPITCH 136

typedef __attribute__((ext_vector_type(8))) short bf16x8;
typedef __attribute__((ext_vector_type(4))) float f32x4;

__device__ __forceinline__ float lrelu(float x) { return (x >= 0.f) ? x : 0.01f * x; }

__device__ __forceinline__ unsigned short f2bf(float x) {
  unsigned u = __float_as_uint(x);
  return (unsigned short)((u + 0x7fffu + ((u >> 16) & 1u)) >> 16);
}
__device__ __forceinline__ unsigned pk2(float a, float b) {
  return (unsigned)f2bf(a) | ((unsigned)f2bf(b) << 16);
}
__device__ __forceinline__ float bf2f(unsigned short u) {
  return __uint_as_float(((unsigned)u) << 16);
}

// ---------------- Threefry-2x32 (bit-exact vs JAX, partitionable XOR mode) -----------
__device__ __forceinline__ void tf2x32(unsigned k0, unsigned k1,
                                       unsigned x0, unsigned x1,
                                       unsigned& o0, unsigned& o1) {
  unsigned ks2 = k0 ^ k1 ^ 0x1BD11BDAu;
  x0 += k0; x1 += k1;
#define TFR(r) { x0 += x1; x1 = (x1 << r) | (x1 >> (32 - r)); x1 ^= x0; }
  TFR(13) TFR(15) TFR(26) TFR(6)   x0 += k1;  x1 += ks2 + 1u;
  TFR(17) TFR(29) TFR(16) TFR(24)  x0 += ks2; x1 += k0 + 2u;
  TFR(13) TFR(15) TFR(26) TFR(6)   x0 += k0;  x1 += k1 + 3u;
  TFR(17) TFR(29) TFR(16) TFR(24)  x0 += k1;  x1 += ks2 + 4u;
  TFR(13) TFR(15) TFR(26) TFR(6)   x0 += ks2; x1 += k0 + 5u;
#undef TFR
  o0 = x0; o1 = x1;
}

__device__ __forceinline__ float bits_to_normal(unsigned bits) {
  float f = __uint_as_float((bits >> 9) | 0x3f800000u) - 1.0f;  // [0,1)
  const float lo = -0.99999994f;                                 // nextafter(-1,0)
  float x = fmaxf(lo, fmaf(f, 2.0f, lo));
  float w = -log1pf(-x * x);
  float p;
  if (w < 5.0f) {
    w = w - 2.5f;
    p = 2.81022636e-08f;
    p = fmaf(p, w, 3.43273939e-07f);
    p = fmaf(p, w, -3.5233877e-06f);
    p = fmaf(p, w, -4.39150654e-06f);
    p = fmaf(p, w, 0.00021858087f);
    p = fmaf(p, w, -0.00125372503f);
    p = fmaf(p, w, -0.00417768164f);
    p = fmaf(p, w, 0.246640727f);
    p = fmaf(p, w, 1.50140941f);
  } else {
    w = sqrtf(w) - 3.0f;
    p = -0.000200214257f;
    p = fmaf(p, w, 0.000100950558f);
    p = fmaf(p, w, 0.00134934322f);
    p = fmaf(p, w, -0.00367342844f);
    p = fmaf(p, w, 0.00573950773f);
    p = fmaf(p, w, -0.0076224613f);
    p = fmaf(p, w, 0.00943887047f);
    p = fmaf(p, w, 1.00167406f);
    p = fmaf(p, w, 2.83297682f);
  }
  return 1.41421356237f * (p * x);
}

struct SmemGemm {
  unsigned short Xt[64 * XPITCH];
  float aColP[132], bColP[132];
  float bsum[128], bssq[128];
};

struct Params {
  const float *data, *rtg, *rth, *I_HG, *v;
  const float *W1g, *b1g, *g1g, *be1g, *W2g, *b2g, *g2g, *be2g;
  const float *W1h, *b1h, *g1h, *be1h, *W2h, *b2h, *g2h, *be2h;
  const float *Wo1, *bo1, *Wa, *ba, *Wm, *bm;
  unsigned short *Ybf, *WtG;
  float *stats1, *stats2, *statsh1, *statsh2, *scaleg, *scaleh;
  float *y1h, *y2h, *partials;
  unsigned *cnt;
  float *out;
};

// ---------------- prep: scales + W->bf16 transpose + zero counters ----------------
__global__ __launch_bounds__(256) void k_prepW(Params p) {
  const int bid = blockIdx.x, tid = threadIdx.x;
  if (bid == 0 && tid < 4) p.cnt[tid] = 0;
  for (int i = bid * 256 + tid; i < ROWS + HROWS; i += 256 * 256) {
    if (i < ROWS) {
      float4 r = ((const float4*)p.rtg)[i];
      p.scaleg[i] = (r.x + r.y + r.z + r.w) * 0.25f;
    } else {
      float4 r = ((const float4*)p.rth)[i - ROWS];
      p.scaleh[i - ROWS] = (r.x + r.y + r.z + r.w) * 0.25f;
    }
  }
  {
    int i = bid * 256 + tid;
    if (i < 32768) {
      int w = i >> 14, rem = i & 16383;
      int c = rem & 127, k = rem >> 7;
      const float* W = w ? p.W2g : p.W1g;
      p.WtG[w * 16384 + c * 128 + k] = f2bf(W[k * 128 + c]);
    }
  }
}

// ---------------- edge GEMM (3-tile pipelined) + fused last-block stats reduce -------
template <int MODE>
__device__ __forceinline__ void edge_gemm_phase(
    const Params& p, SmemGemm& sg, int bid, int nblk, int tid,
    const unsigned short* WtG, const unsigned short* Yin, unsigned short* Yout,
    const float* bias, const float* gmm, const float* beta,
    const float* stats_in) {
  const int lane = tid & 63, wid = tid >> 6;
  const int l15 = lane & 15, lq = lane >> 4;
  const int cb = wid * 32;
  const int rsi = tid >> 2, q = tid & 3, k0 = q * 32;

  if (tid < 128) {
    sg.bsum[tid] = 0.f; sg.bssq[tid] = 0.f;
    if (MODE == 1) {
      float s = stats_in[tid], ss = stats_in[128 + tid];
      float mu = s * (1.f / ROWS);
      float var = fmaxf(ss * (1.f / ROWS) - mu * mu, 0.f);
      float rs = 1.f / sqrtf(var + EPSF);
      float a = rs * gmm[tid];
      int pi = tid + (tid >> 5);
      sg.aColP[pi] = a; sg.bColP[pi] = beta[tid] - mu * a;
    }
  }

  const unsigned short* WA = WtG + (cb + l15) * 128 + lq * 8;
  bf16x8 a0[4], a1[4];
#pragma unroll
  for (int kc = 0; kc < 4; ++kc) {
    a0[kc] = *(const bf16x8*)(WA + kc * 32);
    a1[kc] = *(const bf16x8*)(WA + 16 * 128 + kc * 32);
  }
  float4 bi0 = *(const float4*)&bias[cb + lq * 4];
  float4 bi1 = *(const float4*)&bias[cb + 16 + lq * 4];
  f32x4 bv0 = {bi0.x, bi0.y, bi0.z, bi0.w};
  f32x4 bv1 = {bi1.x, bi1.y, bi1.z, bi1.w};
  f32x4 s0 = {0.f,0.f,0.f,0.f}, ss0 = {0.f,0.f,0.f,0.f};
  f32x4 s1 = {0.f,0.f,0.f,0.f}, ss1 = {0.f,0.f,0.f,0.f};

  float4 ra[4], rb[4];
  uint4  rw[4];

  auto LOAD = [&](int tile) {
    if (MODE == 0) {
      int g = tile * 64 + rsi;
      int b = g / EE; int e = g - b * EE;
      int i = e / 99; int jj = e - i * 99; int j = jj + ((jj >= i) ? 1 : 0);
      int vsrc = (q < 2) ? ((b * NN + i) * FF + q * 32)
                         : ((b * NN + j) * FF + (q - 2) * 32);
#pragma unroll
      for (int i2 = 0; i2 < 4; ++i2) {
        ra[i2] = *(const float4*)&p.v[vsrc + i2 * 8];
        rb[i2] = *(const float4*)&p.v[vsrc + i2 * 8 + 4];
      }
    } else {
      const unsigned short* src = Yin + (size_t)(tile * 64 + rsi) * 128 + k0;
#pragma unroll
      for (int i2 = 0; i2 < 4; ++i2) rw[i2] = *(const uint4*)&src[i2 * 8];
    }
  };
  auto WRITE = [&]() {
    if (MODE == 0) {
#pragma unroll
      for (int i2 = 0; i2 < 4; ++i2) {
        uint4 pk;
        pk.x = pk2(ra[i2].x, ra[i2].y); pk.y = pk2(ra[i2].z, ra[i2].w);
        pk.z = pk2(rb[i2].x, rb[i2].y); pk.w = pk2(rb[i2].z, rb[i2].w);
        *(uint4*)&sg.Xt[rsi * XPITCH + k0 + i2 * 8] = pk;
      }
    } else {
#pragma unroll
      for (int i2 = 0; i2 < 4; ++i2) {
        unsigned rr[4] = {rw[i2].x, rw[i2].y, rw[i2].z, rw[i2].w};
        unsigned ow[4];
#pragma unroll
        for (int u = 0; u < 4; ++u) {
          int k = k0 + i2 * 8 + u * 2;
          int p1 = k + (k >> 5);
          float xl = __uint_as_float(rr[u] << 16);
          float xh = __uint_as_float(rr[u] & 0xffff0000u);
          xl = lrelu(fmaf(xl, sg.aColP[p1], sg.bColP[p1]));
          xh = lrelu(fmaf(xh, sg.aColP[p1 + 1], sg.bColP[p1 + 1]));
          ow[u] = pk2(xl, xh);
        }
        uint4 pk; pk.x = ow[0]; pk.y = ow[1]; pk.z = ow[2]; pk.w = ow[3];
        *(uint4*)&sg.Xt[rsi * XPITCH + k0 + i2 * 8] = pk;
      }
    }
  };

  if (MODE == 1) __syncthreads();

  LOAD(bid);
  for (int t = bid; t < NTILE; t += nblk) {
    if (t != bid) __syncthreads();
    WRITE();
    if (t + nblk < NTILE) LOAD(t + nblk);
    __syncthreads();

    f32x4 acc[2][4];
#pragma unroll
    for (int a = 0; a < 2; ++a)
#pragma unroll
      for (int b2 = 0; b2 < 4; ++b2) acc[a][b2] = (f32x4){0.f, 0.f, 0.f, 0.f};
    const unsigned short* Bb = &sg.Xt[l15 * XPITCH + lq * 8];
#pragma unroll
    for (int kc = 0; kc < 4; ++kc) {
      int ko = kc * 32;
#pragma unroll
      for (int rbi = 0; rbi < 4; ++rbi) {
        bf16x8 bfr = *(const bf16x8*)(Bb + rbi * 16 * XPITCH + ko);
        acc[0][rbi] = __builtin_amdgcn_mfma_f32_16x16x32_bf16(a0[kc], bfr, acc[0][rbi], 0, 0, 0);
        acc[1][rbi] = __builtin_amdgcn_mfma_f32_16x16x32_bf16(a1[kc], bfr, acc[1][rbi], 0, 0, 0);
      }
    }

    int r0 = t * 64;
#pragma unroll
    for (int rbi = 0; rbi < 4; ++rbi) {
      size_t r = (size_t)(r0 + rbi * 16 + l15);
      f32x4 y0 = acc[0][rbi] + bv0;
      f32x4 y1 = acc[1][rbi] + bv1;
      uint2 w0; w0.x = pk2(y0.x, y0.y); w0.y = pk2(y0.z, y0.w);
      uint2 w1; w1.x = pk2(y1.x, y1.y); w1.y = pk2(y1.z, y1.w);
      *(uint2*)&Yout[r * 128 + cb + lq * 4] = w0;
      *(uint2*)&Yout[r * 128 + cb + 16 + lq * 4] = w1;
      s0 += y0; ss0 += y0 * y0;
      s1 += y1; ss1 += y1 * y1;
    }
  }

#pragma unroll
  for (int u = 0; u < 4; ++u) {
    atomicAdd(&sg.bsum[cb + lq * 4 + u], s0[u]);
    atomicAdd(&sg.bssq[cb + lq * 4 + u], ss0[u]);
    atomicAdd(&sg.bsum[cb + 16 + lq * 4 + u], s1[u]);
    atomicAdd(&sg.bssq[cb + 16 + lq * 4 + u], ss1[u]);
  }
  __syncthreads();
  if (tid < 128) {
    p.partials[(size_t)bid * 256 + tid] = sg.bsum[tid];
    p.partials[(size_t)bid * 256 + 128 + tid] = sg.bssq[tid];
  }
}

// last finishing block reduces partials -> stats (saves 2 launches per gemm)
__device__ __forceinline__ void lastblock_stats(const Params& p, float* stats,
                                                unsigned* cnt, int nblk, int tid) {
  __shared__ int isLast;
  __threadfence();
  __syncthreads();
  if (tid == 0) isLast = (atomicAdd(cnt, 1u) == (unsigned)(nblk - 1));
  __syncthreads();
  if (isLast) {
    __threadfence();
    float s = 0.f;
#pragma unroll 5
    for (int r = 0; r < nblk; ++r) s += p.partials[(size_t)r * 256 + tid];
    stats[tid] = s;
  }
}

__global__ __launch_bounds__(256, 4) void k_gemm0W(Params p) {
  __shared__ __align__(16) SmemGemm sg;
  edge_gemm_phase<0>(p, sg, blockIdx.x, GEMMB, threadIdx.x, p.WtG, nullptr,
                     p.Ybf, p.b1g, nullptr, nullptr, nullptr);
  lastblock_stats(p, p.stats1, p.cnt + 0, GEMMB, threadIdx.x);
}
__global__ __launch_bounds__(256, 4) void k_gemm1W(Params p) {
  __shared__ __align__(16) SmemGemm sg;
  edge_gemm_phase<1>(p, sg, blockIdx.x, GEMMB, threadIdx.x, p.WtG + 16384,
                     p.Ybf, p.Ybf, p.b2g, p.g1g, p.be1g, p.stats1);
  lastblock_stats(p, p.stats2, p.cnt + 1, GEMMB, threadIdx.x);
}

// ---------------- h1 / h2 with fused last-block column stats ----------------
__device__ __forceinline__ void lastblock_colstats(const float* X, float* stats,
                                                   unsigned* cnt, int nblk, int tid) {
  __shared__ int isLast;
  __shared__ float rs[128], rss[128];
  __threadfence();
  __syncthreads();
  if (tid == 0) isLast = (atomicAdd(cnt, 1u) == (unsigned)(nblk - 1));
  __syncthreads();
  if (isLast) {
    __threadfence();
    int c = tid & 127, half = tid >> 7;
    float s = 0.f, ss = 0.f;
    for (int r = half * 400; r < half * 400 + 400; ++r) {
      float x = X[(size_t)r * 128 + c];
      s += x; ss += x * x;
    }
    if (half) { rs[c] = s; rss[c] = ss; }
    __syncthreads();
    if (!half) { stats[c] = s + rs[c]; stats[128 + c] = ss + rss[c]; }
  }
}

__global__ __launch_bounds__(256) void k_h1W(Params p) {
  __shared__ float prerow[2][FF];
  const int bid = blockIdx.x, tid = threadIdx.x;
  const int sub = tid >> 7, ht = tid & 127;
  const int bm = bid * 2 + sub;                 // grid 400 -> bm < 800 always
  const int b = bm / MM, m = bm - b * MM;
  if (ht < FF) {
    float s = 0.f;
    for (int n = 0; n < NN; ++n)
      s = fmaf(p.I_HG[(b * NN + n) * MM + m], p.v[(b * NN + n) * FF + ht], s);
    prerow[sub][ht] = s;
  }
  __syncthreads();
  float y = p.b1h[ht];
  for (int f = 0; f < FF; ++f) y = fmaf(prerow[sub][f], p.W1h[f * 128 + ht], y);
  p.y1h[bm * 128 + ht] = y;
  lastblock_colstats(p.y1h, p.statsh1, p.cnt + 2, 400, tid);
}

__global__ __launch_bounds__(256) void k_h2W(Params p) {
  __shared__ float trow[2][128];
  const int bid = blockIdx.x, tid = threadIdx.x;
  const int sub = tid >> 7, ht = tid & 127;
  const int bm = bid * 2 + sub;
  float s = p.statsh1[ht], ss = p.statsh1[128 + ht];
  float mu = s * (1.f / HROWS);
  float var = fmaxf(ss * (1.f / HROWS) - mu * mu, 0.f);
  float rs = 1.f / sqrtf(var + EPSF);
  float a = rs * p.g1h[ht]; float bc = p.be1h[ht] - mu * a;
  trow[sub][ht] = lrelu(p.y1h[bm * 128 + ht] * a + bc);
  __syncthreads();
  float y = p.b2h[ht];
  for (int f = 0; f < 128; ++f) y = fmaf(trow[sub][f], p.W2h[f * 128 + ht], y);
  p.y2h[bm * 128 + ht] = y;
  lastblock_colstats(p.y2h, p.statsh2, p.cnt + 3, 400, tid);
}

// ---------------- fused tail: recv + h3 + ve + out (one block-half per bn) -----------
struct SmemFin {
  float cat[2][256];            // [0:128)=hidden_g, [128:256)=hidden_hg
  float vres[2][128];
  float lgs[2][KK], mrow[2][KK * DD], alsh[2][KK], vcore[2][DD];
  float nz[2][8][2], ins[2][8][2];
};

__global__ __launch_bounds__(256) void k_finW(Params p) {
  __shared__ __align__(16) SmemFin sm;
  const int tid = threadIdx.x;
  const int sub = tid >> 7, ht = tid & 127;
  const int bn = blockIdx.x * 2 + sub;          // grid 800 -> bn < 1600 always
  const int b = bn / NN, n = bn - b * NN;

  // noise (independent; consumed after the barrier below)
  if (ht < 16) {
    int s = ht >> 1, d = ht & 1;
    unsigned fk0, fk1;
    tf2x32(0u, 1234u, 0u, (unsigned)s, fk0, fk1);
    unsigned flat = (unsigned)(bn * 2 + d);
    unsigned o0, o1;
    tf2x32(fk0, fk1, 0u, flat, o0, o1);
    sm.nz[sub][s][d] = bits_to_normal(o0 ^ o1);
  }

  // recv -> cat[sub][0:128)
  {
    float s = p.stats2[ht], ss = p.stats2[128 + ht];
    float mu = s * (1.f / ROWS);
    float var = fmaxf(ss * (1.f / ROWS) - mu * mu, 0.f);
    float rs = 1.f / sqrtf(var + EPSF);
    float a = rs * p.g2g[ht]; float bc = p.be2g[ht] - mu * a;
    float sv = (ht >= 64) ? p.v[(b * NN + n) * FF + (ht - 64)] : 0.f;
    float acc = 0.f;
#pragma unroll 4
    for (int i = 0; i < NN; ++i) {
      if (i == n) continue;
      int e = i * 99 + ((n < i) ? n : n - 1);
      int row = b * EE + e;
      float y = bf2f(p.Ybf[(size_t)row * 128 + ht]);
      float msgv = lrelu(y * a + bc);
      float pre = (ht < 64) ? p.v[(b * NN + i) * FF + ht] : sv;
      acc += lrelu(fmaf(msgv, p.scaleg[row], pre));
    }
    sm.cat[sub][ht] = acc * 0.5f;
  }
  // h3 -> cat[sub][128:256)
  {
    float s = p.statsh2[ht], ss = p.statsh2[128 + ht];
    float mu = s * (1.f / HROWS);
    float var = fmaxf(ss * (1.f / HROWS) - mu * mu, 0.f);
    float rs = 1.f / sqrtf(var + EPSF);
    float a = rs * p.g2h[ht]; float bc = p.be2h[ht] - mu * a;
    float acc = 0.f;
    for (int m = 0; m < MM; ++m) {
      float x = lrelu(p.y2h[(b * MM + m) * 128 + ht] * a + bc);
      acc = fmaf(x * p.scaleh[b * MM + m], p.I_HG[(b * NN + n) * MM + m], acc);
    }
    sm.cat[sub][128 + ht] = acc * 0.5f;
  }
  __syncthreads();

  // ve: v = lrelu(cat @ Wo1 + bo1)
  float vv = p.bo1[ht];
  for (int k = 0; k < 256; ++k)
    vv = fmaf(sm.cat[sub][k], p.Wo1[k * 128 + ht], vv);
  sm.vres[sub][ht] = lrelu(vv);
  __syncthreads();
  if (ht < KK) {
    float s = p.ba[ht];
    for (int f = 0; f < 128; ++f) s = fmaf(sm.vres[sub][f], p.Wa[f * KK + ht], s);
    sm.lgs[sub][ht] = s;
  } else if (ht >= 64 && ht < 64 + KK * DD) {
    int c = ht - 64;
    float s = p.bm[c];
    for (int f = 0; f < 128; ++f) s = fmaf(sm.vres[sub][f], p.Wm[f * (KK * DD) + c], s);
    sm.mrow[sub][c] = s;
  }
  __syncthreads();
  if (ht < KK) {
    float mx = sm.lgs[sub][0];
    for (int k2 = 1; k2 < KK; ++k2) mx = fmaxf(mx, sm.lgs[sub][k2]);
    float se = 0.f;
    for (int k2 = 0; k2 < KK; ++k2) se += expf(sm.lgs[sub][k2] - mx);
    sm.alsh[sub][ht] = expf(sm.lgs[sub][ht] - mx) / se;
  }
  __syncthreads();
  if (ht < DD) {
    float s = 0.f;
    for (int k2 = 0; k2 < KK; ++k2)
      s = fmaf(sm.alsh[sub][k2], sm.mrow[sub][k2 * DD + ht], s);
    sm.vcore[sub][ht] = s;
  }
  __syncthreads();

  // out: preds / alphas / mus / sigmas (all operands in LDS)
  if (ht < 2) {
    int d = ht;
    float pp = p.data[bn * 16 + d];             // data[b,n,0,d]
    float core = sm.vcore[sub][d];
    for (int s = 0; s < 8; ++s) {
      sm.ins[sub][s][d] = pp;
      pp = (pp + core) + sm.nz[sub][s][d];
      p.out[(bn * 8 + s) * 2 + d] = pp;
    }
  }
  __syncthreads();
  for (int q = ht; q < 160; q += 128)
    p.out[25600 + bn * 160 + q] = sm.alsh[sub][q % KK];
  for (int q = ht; q < 320; q += 128) {
    int s = q / 40, kd = q - s * 40, d = kd & 1;
    p.out[281600 + bn * 320 + q] = sm.mrow[sub][kd] + sm.ins[sub][s][d];
  }
  for (int q = ht; q < 320; q += 128) p.out[793600 + bn * 320 + q] = 1.0f;
}

extern "C" void kernel_launch(void* const* d_in, const int* in_sizes, int n_in,
                              void* d_out, int out_size, void* d_ws, size_t ws_size,
                              hipStream_t stream) {
  char* wsb = (char*)d_ws;

  Params p;
  p.data = (const float*)d_in[0];
  p.rtg  = (const float*)d_in[3];
  p.rth  = (const float*)d_in[4];
  p.I_HG = (const float*)d_in[5];
  p.v    = (const float*)d_in[6];
  p.W1g  = (const float*)d_in[7];
  p.b1g  = (const float*)d_in[8];
  p.g1g  = (const float*)d_in[9];
  p.be1g = (const float*)d_in[10];
  p.W2g  = (const float*)d_in[11];
  p.b2g  = (const float*)d_in[12];
  p.g2g  = (const float*)d_in[13];
  p.be2g = (const float*)d_in[14];
  p.W1h  = (const float*)d_in[15];
  p.b1h  = (const float*)d_in[16];
  p.g1h  = (const float*)d_in[17];
  p.be1h = (const float*)d_in[18];
  p.W2h  = (const float*)d_in[19];
  p.b2h  = (const float*)d_in[20];
  p.g2h  = (const float*)d_in[21];
  p.be2h = (const float*)d_in[22];
  p.Wo1  = (const float*)d_in[23];
  p.bo1  = (const float*)d_in[24];
  p.Wa   = (const float*)d_in[25];
  p.ba   = (const float*)d_in[26];
  p.Wm   = (const float*)d_in[27];
  p.bm   = (const float*)d_in[28];

  p.Ybf     = (unsigned short*)wsb;                                  // 40,550,400 B
  p.stats1  = (float*)(wsb + 40550400);                              // 4x256 f32
  p.stats2  = p.stats1 + 256;
  p.statsh1 = p.stats2 + 256;
  p.statsh2 = p.statsh1 + 256;
  p.scaleg  = (float*)(wsb + 40550400 + 4096);                       // ROWS f32
  p.scaleh  = p.scaleg + ROWS;                                       // HROWS f32
  p.y1h     = p.scaleh + HROWS;                                      // 800*128 f32
  p.y2h     = p.y1h + HROWS * 128;
  p.WtG     = (unsigned short*)(p.y2h + HROWS * 128);                // 2*16384 bf16
  p.partials = (float*)(p.WtG + 2 * 16384);                          // 825*256 f32
  p.cnt     = (unsigned*)(p.partials + (size_t)GEMMB * 256);         // 4 u32
  p.out     = (float*)d_out;

  k_prepW<<<256, 256, 0, stream>>>(p);
  k_gemm0W<<<GEMMB, 256, 0, stream>>>(p);
  k_gemm1W<<<GEMMB, 256, 0, stream>>>(p);
  k_h1W<<<400, 256, 0, stream>>>(p);
  k_h2W<<<400, 256, 0, stream>>>(p);
  k_finW<<<800, 256, 0, stream>>>(p);
}

// Round 12
// 483.220 us; speedup vs baseline: 1.2929x; 1.2929x over previous
//
#include <hip/hip_runtime.h>

// Problem constants: B=16,N=100,E=9900,M=50,F=64,H=128,K=20,D=2,T=8,S=8
#define BB 16
#define NN 100
#define EE 9900
#define MM 50
#define FF 64
#define KK 20
#define DD 2
#define ROWS (BB*EE)      // 158400 edge rows
#define HROWS (BB*MM)     // 800 hyper rows
#define BN_CNT (BB*NN)    // 1600
#define NTILE (ROWS/64)   // 2475 tiles of 64 rows
#define GEMMB 512         // gemm grid (R10-proven: 2 blocks/CU, VGPR 88, no spill)
#define EPSF 1e-5f
#define XPITCH 136

typedef __attribute__((ext_vector_type(8))) short bf16x8;
typedef __attribute__((ext_vector_type(4))) float f32x4;

__device__ __forceinline__ float lrelu(float x) { return (x >= 0.f) ? x : 0.01f * x; }

__device__ __forceinline__ unsigned short f2bf(float x) {
  unsigned u = __float_as_uint(x);
  return (unsigned short)((u + 0x7fffu + ((u >> 16) & 1u)) >> 16);
}
__device__ __forceinline__ unsigned pk2(float a, float b) {
  return (unsigned)f2bf(a) | ((unsigned)f2bf(b) << 16);
}
__device__ __forceinline__ float bf2f(unsigned short u) {
  return __uint_as_float(((unsigned)u) << 16);
}

// ---------------- Threefry-2x32 (bit-exact vs JAX, partitionable XOR mode) -----------
__device__ __forceinline__ void tf2x32(unsigned k0, unsigned k1,
                                       unsigned x0, unsigned x1,
                                       unsigned& o0, unsigned& o1) {
  unsigned ks2 = k0 ^ k1 ^ 0x1BD11BDAu;
  x0 += k0; x1 += k1;
#define TFR(r) { x0 += x1; x1 = (x1 << r) | (x1 >> (32 - r)); x1 ^= x0; }
  TFR(13) TFR(15) TFR(26) TFR(6)   x0 += k1;  x1 += ks2 + 1u;
  TFR(17) TFR(29) TFR(16) TFR(24)  x0 += ks2; x1 += k0 + 2u;
  TFR(13) TFR(15) TFR(26) TFR(6)   x0 += k0;  x1 += k1 + 3u;
  TFR(17) TFR(29) TFR(16) TFR(24)  x0 += k1;  x1 += ks2 + 4u;
  TFR(13) TFR(15) TFR(26) TFR(6)   x0 += ks2; x1 += k0 + 5u;
#undef TFR
  o0 = x0; o1 = x1;
}

__device__ __forceinline__ float bits_to_normal(unsigned bits) {
  float f = __uint_as_float((bits >> 9) | 0x3f800000u) - 1.0f;  // [0,1)
  const float lo = -0.99999994f;                                 // nextafter(-1,0)
  float x = fmaxf(lo, fmaf(f, 2.0f, lo));
  float w = -log1pf(-x * x);
  float p;
  if (w < 5.0f) {
    w = w - 2.5f;
    p = 2.81022636e-08f;
    p = fmaf(p, w, 3.43273939e-07f);
    p = fmaf(p, w, -3.5233877e-06f);
    p = fmaf(p, w, -4.39150654e-06f);
    p = fmaf(p, w, 0.00021858087f);
    p = fmaf(p, w, -0.00125372503f);
    p = fmaf(p, w, -0.00417768164f);
    p = fmaf(p, w, 0.246640727f);
    p = fmaf(p, w, 1.50140941f);
  } else {
    w = sqrtf(w) - 3.0f;
    p = -0.000200214257f;
    p = fmaf(p, w, 0.000100950558f);
    p = fmaf(p, w, 0.00134934322f);
    p = fmaf(p, w, -0.00367342844f);
    p = fmaf(p, w, 0.00573950773f);
    p = fmaf(p, w, -0.0076224613f);
    p = fmaf(p, w, 0.00943887047f);
    p = fmaf(p, w, 1.00167406f);
    p = fmaf(p, w, 2.83297682f);
  }
  return 1.41421356237f * (p * x);
}

struct SmemGemm {
  unsigned short Xt[64 * XPITCH];
  float aColP[132], bColP[132];
  float bsum[128], bssq[128];
};

struct Params {
  const float *data, *rtg, *rth, *I_HG, *v;
  const float *W1g, *b1g, *g1g, *be1g, *W2g, *b2g, *g2g, *be2g;
  const float *W1h, *b1h, *g1h, *be1h, *W2h, *b2h, *g2h, *be2h;
  const float *Wo1, *bo1, *Wa, *ba, *Wm, *bm;
  unsigned short *Ybf, *WtG;
  float *stats1, *stats2, *statsh1, *statsh2, *scaleg, *scaleh;
  float *y1h, *y2h, *partials;
  unsigned *cnt;
  float *out;
};

// ---------------- prep: scales + W->bf16 transpose + zero counters ----------------
__global__ __launch_bounds__(256) void k_prepW(Params p) {
  const int bid = blockIdx.x, tid = threadIdx.x;
  if (bid == 0 && tid < 4) p.cnt[tid] = 0;
  for (int i = bid * 256 + tid; i < ROWS + HROWS; i += 256 * 256) {
    if (i < ROWS) {
      float4 r = ((const float4*)p.rtg)[i];
      p.scaleg[i] = (r.x + r.y + r.z + r.w) * 0.25f;
    } else {
      float4 r = ((const float4*)p.rth)[i - ROWS];
      p.scaleh[i - ROWS] = (r.x + r.y + r.z + r.w) * 0.25f;
    }
  }
  {
    int i = bid * 256 + tid;
    if (i < 32768) {
      int w = i >> 14, rem = i & 16383;
      int c = rem & 127, k = rem >> 7;
      const float* W = w ? p.W2g : p.W1g;
      p.WtG[w * 16384 + c * 128 + k] = f2bf(W[k * 128 + c]);
    }
  }
}

// ---------------- edge GEMM (pipelined) + fused last-block stats reduce -------
template <int MODE>
__device__ __forceinline__ void edge_gemm_phase(
    const Params& p, SmemGemm& sg, int bid, int nblk, int tid,
    const unsigned short* WtG, const unsigned short* Yin, unsigned short* Yout,
    const float* bias, const float* gmm, const float* beta,
    const float* stats_in) {
  const int lane = tid & 63, wid = tid >> 6;
  const int l15 = lane & 15, lq = lane >> 4;
  const int cb = wid * 32;
  const int rsi = tid >> 2, q = tid & 3, k0 = q * 32;

  if (tid < 128) {
    sg.bsum[tid] = 0.f; sg.bssq[tid] = 0.f;
    if (MODE == 1) {
      float s = stats_in[tid], ss = stats_in[128 + tid];
      float mu = s * (1.f / ROWS);
      float var = fmaxf(ss * (1.f / ROWS) - mu * mu, 0.f);
      float rs = 1.f / sqrtf(var + EPSF);
      float a = rs * gmm[tid];
      int pi = tid + (tid >> 5);
      sg.aColP[pi] = a; sg.bColP[pi] = beta[tid] - mu * a;
    }
  }

  const unsigned short* WA = WtG + (cb + l15) * 128 + lq * 8;
  bf16x8 a0[4], a1[4];
#pragma unroll
  for (int kc = 0; kc < 4; ++kc) {
    a0[kc] = *(const bf16x8*)(WA + kc * 32);
    a1[kc] = *(const bf16x8*)(WA + 16 * 128 + kc * 32);
  }
  float4 bi0 = *(const float4*)&bias[cb + lq * 4];
  float4 bi1 = *(const float4*)&bias[cb + 16 + lq * 4];
  f32x4 bv0 = {bi0.x, bi0.y, bi0.z, bi0.w};
  f32x4 bv1 = {bi1.x, bi1.y, bi1.z, bi1.w};
  f32x4 s0 = {0.f,0.f,0.f,0.f}, ss0 = {0.f,0.f,0.f,0.f};
  f32x4 s1 = {0.f,0.f,0.f,0.f}, ss1 = {0.f,0.f,0.f,0.f};

  float4 ra[4], rb[4];
  uint4  rw[4];

  auto LOAD = [&](int tile) {
    if (MODE == 0) {
      int g = tile * 64 + rsi;
      int b = g / EE; int e = g - b * EE;
      int i = e / 99; int jj = e - i * 99; int j = jj + ((jj >= i) ? 1 : 0);
      int vsrc = (q < 2) ? ((b * NN + i) * FF + q * 32)
                         : ((b * NN + j) * FF + (q - 2) * 32);
#pragma unroll
      for (int i2 = 0; i2 < 4; ++i2) {
        ra[i2] = *(const float4*)&p.v[vsrc + i2 * 8];
        rb[i2] = *(const float4*)&p.v[vsrc + i2 * 8 + 4];
      }
    } else {
      const unsigned short* src = Yin + (size_t)(tile * 64 + rsi) * 128 + k0;
#pragma unroll
      for (int i2 = 0; i2 < 4; ++i2) rw[i2] = *(const uint4*)&src[i2 * 8];
    }
  };
  auto WRITE = [&]() {
    if (MODE == 0) {
#pragma unroll
      for (int i2 = 0; i2 < 4; ++i2) {
        uint4 pk;
        pk.x = pk2(ra[i2].x, ra[i2].y); pk.y = pk2(ra[i2].z, ra[i2].w);
        pk.z = pk2(rb[i2].x, rb[i2].y); pk.w = pk2(rb[i2].z, rb[i2].w);
        *(uint4*)&sg.Xt[rsi * XPITCH + k0 + i2 * 8] = pk;
      }
    } else {
#pragma unroll
      for (int i2 = 0; i2 < 4; ++i2) {
        unsigned rr[4] = {rw[i2].x, rw[i2].y, rw[i2].z, rw[i2].w};
        unsigned ow[4];
#pragma unroll
        for (int u = 0; u < 4; ++u) {
          int k = k0 + i2 * 8 + u * 2;
          int p1 = k + (k >> 5);
          float xl = __uint_as_float(rr[u] << 16);
          float xh = __uint_as_float(rr[u] & 0xffff0000u);
          xl = lrelu(fmaf(xl, sg.aColP[p1], sg.bColP[p1]));
          xh = lrelu(fmaf(xh, sg.aColP[p1 + 1], sg.bColP[p1 + 1]));
          ow[u] = pk2(xl, xh);
        }
        uint4 pk; pk.x = ow[0]; pk.y = ow[1]; pk.z = ow[2]; pk.w = ow[3];
        *(uint4*)&sg.Xt[rsi * XPITCH + k0 + i2 * 8] = pk;
      }
    }
  };

  if (MODE == 1) __syncthreads();

  LOAD(bid);
  for (int t = bid; t < NTILE; t += nblk) {
    if (t != bid) __syncthreads();
    WRITE();
    if (t + nblk < NTILE) LOAD(t + nblk);
    __syncthreads();

    f32x4 acc[2][4];
#pragma unroll
    for (int a = 0; a < 2; ++a)
#pragma unroll
      for (int b2 = 0; b2 < 4; ++b2) acc[a][b2] = (f32x4){0.f, 0.f, 0.f, 0.f};
    const unsigned short* Bb = &sg.Xt[l15 * XPITCH + lq * 8];
#pragma unroll
    for (int kc = 0; kc < 4; ++kc) {
      int ko = kc * 32;
#pragma unroll
      for (int rbi = 0; rbi < 4; ++rbi) {
        bf16x8 bfr = *(const bf16x8*)(Bb + rbi * 16 * XPITCH + ko);
        acc[0][rbi] = __builtin_amdgcn_mfma_f32_16x16x32_bf16(a0[kc], bfr, acc[0][rbi], 0, 0, 0);
        acc[1][rbi] = __builtin_amdgcn_mfma_f32_16x16x32_bf16(a1[kc], bfr, acc[1][rbi], 0, 0, 0);
      }
    }

    int r0 = t * 64;
#pragma unroll
    for (int rbi = 0; rbi < 4; ++rbi) {
      size_t r = (size_t)(r0 + rbi * 16 + l15);
      f32x4 y0 = acc[0][rbi] + bv0;
      f32x4 y1 = acc[1][rbi] + bv1;
      uint2 w0; w0.x = pk2(y0.x, y0.y); w0.y = pk2(y0.z, y0.w);
      uint2 w1; w1.x = pk2(y1.x, y1.y); w1.y = pk2(y1.z, y1.w);
      *(uint2*)&Yout[r * 128 + cb + lq * 4] = w0;
      *(uint2*)&Yout[r * 128 + cb + 16 + lq * 4] = w1;
      s0 += y0; ss0 += y0 * y0;
      s1 += y1; ss1 += y1 * y1;
    }
  }

#pragma unroll
  for (int u = 0; u < 4; ++u) {
    atomicAdd(&sg.bsum[cb + lq * 4 + u], s0[u]);
    atomicAdd(&sg.bssq[cb + lq * 4 + u], ss0[u]);
    atomicAdd(&sg.bsum[cb + 16 + lq * 4 + u], s1[u]);
    atomicAdd(&sg.bssq[cb + 16 + lq * 4 + u], ss1[u]);
  }
  __syncthreads();
  if (tid < 128) {
    p.partials[(size_t)bid * 256 + tid] = sg.bsum[tid];
    p.partials[(size_t)bid * 256 + 128 + tid] = sg.bssq[tid];
  }
}

// last finishing block reduces partials -> stats (saves 2 launches per gemm)
__device__ __forceinline__ void lastblock_stats(const Params& p, float* stats,
                                                unsigned* cnt, int nblk, int tid) {
  __shared__ int isLast;
  __threadfence();
  __syncthreads();
  if (tid == 0) isLast = (atomicAdd(cnt, 1u) == (unsigned)(nblk - 1));
  __syncthreads();
  if (isLast) {
    __threadfence();
    float s = 0.f;
#pragma unroll 4
    for (int r = 0; r < nblk; ++r) s += p.partials[(size_t)r * 256 + tid];
    stats[tid] = s;
  }
}

__global__ __launch_bounds__(256, 2) void k_gemm0W(Params p) {
  __shared__ __align__(16) SmemGemm sg;
  edge_gemm_phase<0>(p, sg, blockIdx.x, GEMMB, threadIdx.x, p.WtG, nullptr,
                     p.Ybf, p.b1g, nullptr, nullptr, nullptr);
  lastblock_stats(p, p.stats1, p.cnt + 0, GEMMB, threadIdx.x);
}
__global__ __launch_bounds__(256, 2) void k_gemm1W(Params p) {
  __shared__ __align__(16) SmemGemm sg;
  edge_gemm_phase<1>(p, sg, blockIdx.x, GEMMB, threadIdx.x, p.WtG + 16384,
                     p.Ybf, p.Ybf, p.b2g, p.g1g, p.be1g, p.stats1);
  lastblock_stats(p, p.stats2, p.cnt + 1, GEMMB, threadIdx.x);
}

// ---------------- h1 / h2 with fused last-block column stats ----------------
__device__ __forceinline__ void lastblock_colstats(const float* X, float* stats,
                                                   unsigned* cnt, int nblk, int tid) {
  __shared__ int isLast;
  __shared__ float rs[128], rss[128];
  __threadfence();
  __syncthreads();
  if (tid == 0) isLast = (atomicAdd(cnt, 1u) == (unsigned)(nblk - 1));
  __syncthreads();
  if (isLast) {
    __threadfence();
    int c = tid & 127, half = tid >> 7;
    float s = 0.f, ss = 0.f;
    for (int r = half * 400; r < half * 400 + 400; ++r) {
      float x = X[(size_t)r * 128 + c];
      s += x; ss += x * x;
    }
    if (half) { rs[c] = s; rss[c] = ss; }
    __syncthreads();
    if (!half) { stats[c] = s + rs[c]; stats[128 + c] = ss + rss[c]; }
  }
}

__global__ __launch_bounds__(256) void k_h1W(Params p) {
  __shared__ float prerow[2][FF];
  const int bid = blockIdx.x, tid = threadIdx.x;
  const int sub = tid >> 7, ht = tid & 127;
  const int bm = bid * 2 + sub;                 // grid 400 -> bm < 800 always
  const int b = bm / MM, m = bm - b * MM;
  if (ht < FF) {
    float s = 0.f;
    for (int n = 0; n < NN; ++n)
      s = fmaf(p.I_HG[(b * NN + n) * MM + m], p.v[(b * NN + n) * FF + ht], s);
    prerow[sub][ht] = s;
  }
  __syncthreads();
  float y = p.b1h[ht];
  for (int f = 0; f < FF; ++f) y = fmaf(prerow[sub][f], p.W1h[f * 128 + ht], y);
  p.y1h[bm * 128 + ht] = y;
  lastblock_colstats(p.y1h, p.statsh1, p.cnt + 2, 400, tid);
}

__global__ __launch_bounds__(256) void k_h2W(Params p) {
  __shared__ float trow[2][128];
  const int bid = blockIdx.x, tid = threadIdx.x;
  const int sub = tid >> 7, ht = tid & 127;
  const int bm = bid * 2 + sub;
  float s = p.statsh1[ht], ss = p.statsh1[128 + ht];
  float mu = s * (1.f / HROWS);
  float var = fmaxf(ss * (1.f / HROWS) - mu * mu, 0.f);
  float rs = 1.f / sqrtf(var + EPSF);
  float a = rs * p.g1h[ht]; float bc = p.be1h[ht] - mu * a;
  trow[sub][ht] = lrelu(p.y1h[bm * 128 + ht] * a + bc);
  __syncthreads();
  float y = p.b2h[ht];
  for (int f = 0; f < 128; ++f) y = fmaf(trow[sub][f], p.W2h[f * 128 + ht], y);
  p.y2h[bm * 128 + ht] = y;
  lastblock_colstats(p.y2h, p.statsh2, p.cnt + 3, 400, tid);
}

// ---------------- fused tail: recv + h3 + ve + out (one block-half per bn) -----------
struct SmemFin {
  float cat[2][256];            // [0:128)=hidden_g, [128:256)=hidden_hg
  float vres[2][128];
  float lgs[2][KK], mrow[2][KK * DD], alsh[2][KK], vcore[2][DD];
  float nz[2][8][2], ins[2][8][2];
};

__global__ __launch_bounds__(256) void k_finW(Params p) {
  __shared__ __align__(16) SmemFin sm;
  const int tid = threadIdx.x;
  const int sub = tid >> 7, ht = tid & 127;
  const int bn = blockIdx.x * 2 + sub;          // grid 800 -> bn < 1600 always
  const int b = bn / NN, n = bn - b * NN;

  // noise (independent; consumed after the barrier below)
  if (ht < 16) {
    int s = ht >> 1, d = ht & 1;
    unsigned fk0, fk1;
    tf2x32(0u, 1234u, 0u, (unsigned)s, fk0, fk1);
    unsigned flat = (unsigned)(bn * 2 + d);
    unsigned o0, o1;
    tf2x32(fk0, fk1, 0u, flat, o0, o1);
    sm.nz[sub][s][d] = bits_to_normal(o0 ^ o1);
  }

  // recv -> cat[sub][0:128)
  {
    float s = p.stats2[ht], ss = p.stats2[128 + ht];
    float mu = s * (1.f / ROWS);
    float var = fmaxf(ss * (1.f / ROWS) - mu * mu, 0.f);
    float rs = 1.f / sqrtf(var + EPSF);
    float a = rs * p.g2g[ht]; float bc = p.be2g[ht] - mu * a;
    float sv = (ht >= 64) ? p.v[(b * NN + n) * FF + (ht - 64)] : 0.f;
    float acc = 0.f;
#pragma unroll 4
    for (int i = 0; i < NN; ++i) {
      if (i == n) continue;
      int e = i * 99 + ((n < i) ? n : n - 1);
      int row = b * EE + e;
      float y = bf2f(p.Ybf[(size_t)row * 128 + ht]);
      float msgv = lrelu(y * a + bc);
      float pre = (ht < 64) ? p.v[(b * NN + i) * FF + ht] : sv;
      acc += lrelu(fmaf(msgv, p.scaleg[row], pre));
    }
    sm.cat[sub][ht] = acc * 0.5f;
  }
  // h3 -> cat[sub][128:256)
  {
    float s = p.statsh2[ht], ss = p.statsh2[128 + ht];
    float mu = s * (1.f / HROWS);
    float var = fmaxf(ss * (1.f / HROWS) - mu * mu, 0.f);
    float rs = 1.f / sqrtf(var + EPSF);
    float a = rs * p.g2h[ht]; float bc = p.be2h[ht] - mu * a;
    float acc = 0.f;
    for (int m = 0; m < MM; ++m) {
      float x = lrelu(p.y2h[(b * MM + m) * 128 + ht] * a + bc);
      acc = fmaf(x * p.scaleh[b * MM + m], p.I_HG[(b * NN + n) * MM + m], acc);
    }
    sm.cat[sub][128 + ht] = acc * 0.5f;
  }
  __syncthreads();

  // ve: v = lrelu(cat @ Wo1 + bo1)
  float vv = p.bo1[ht];
  for (int k = 0; k < 256; ++k)
    vv = fmaf(sm.cat[sub][k], p.Wo1[k * 128 + ht], vv);
  sm.vres[sub][ht] = lrelu(vv);
  __syncthreads();
  if (ht < KK) {
    float s = p.ba[ht];
    for (int f = 0; f < 128; ++f) s = fmaf(sm.vres[sub][f], p.Wa[f * KK + ht], s);
    sm.lgs[sub][ht] = s;
  } else if (ht >= 64 && ht < 64 + KK * DD) {
    int c = ht - 64;
    float s = p.bm[c];
    for (int f = 0; f < 128; ++f) s = fmaf(sm.vres[sub][f], p.Wm[f * (KK * DD) + c], s);
    sm.mrow[sub][c] = s;
  }
  __syncthreads();
  if (ht < KK) {
    float mx = sm.lgs[sub][0];
    for (int k2 = 1; k2 < KK; ++k2) mx = fmaxf(mx, sm.lgs[sub][k2]);
    float se = 0.f;
    for (int k2 = 0; k2 < KK; ++k2) se += expf(sm.lgs[sub][k2] - mx);
    sm.alsh[sub][ht] = expf(sm.lgs[sub][ht] - mx) / se;
  }
  __syncthreads();
  if (ht < DD) {
    float s = 0.f;
    for (int k2 = 0; k2 < KK; ++k2)
      s = fmaf(sm.alsh[sub][k2], sm.mrow[sub][k2 * DD + ht], s);
    sm.vcore[sub][ht] = s;
  }
  __syncthreads();

  // out: preds / alphas / mus / sigmas (all operands in LDS)
  if (ht < 2) {
    int d = ht;
    float pp = p.data[bn * 16 + d];             // data[b,n,0,d]
    float core = sm.vcore[sub][d];
    for (int s = 0; s < 8; ++s) {
      sm.ins[sub][s][d] = pp;
      pp = (pp + core) + sm.nz[sub][s][d];
      p.out[(bn * 8 + s) * 2 + d] = pp;
    }
  }
  __syncthreads();
  for (int q = ht; q < 160; q += 128)
    p.out[25600 + bn * 160 + q] = sm.alsh[sub][q % KK];
  for (int q = ht; q < 320; q += 128) {
    int s = q / 40, kd = q - s * 40, d = kd & 1;
    p.out[281600 + bn * 320 + q] = sm.mrow[sub][kd] + sm.ins[sub][s][d];
  }
  for (int q = ht; q < 320; q += 128) p.out[793600 + bn * 320 + q] = 1.0f;
}

extern "C" void kernel_launch(void* const* d_in, const int* in_sizes, int n_in,
                              void* d_out, int out_size, void* d_ws, size_t ws_size,
                              hipStream_t stream) {
  char* wsb = (char*)d_ws;

  Params p;
  p.data = (const float*)d_in[0];
  p.rtg  = (const float*)d_in[3];
  p.rth  = (const float*)d_in[4];
  p.I_HG = (const float*)d_in[5];
  p.v    = (const float*)d_in[6];
  p.W1g  = (const float*)d_in[7];
  p.b1g  = (const float*)d_in[8];
  p.g1g  = (const float*)d_in[9];
  p.be1g = (const float*)d_in[10];
  p.W2g  = (const float*)d_in[11];
  p.b2g  = (const float*)d_in[12];
  p.g2g  = (const float*)d_in[13];
  p.be2g = (const float*)d_in[14];
  p.W1h  = (const float*)d_in[15];
  p.b1h  = (const float*)d_in[16];
  p.g1h  = (const float*)d_in[17];
  p.be1h = (const float*)d_in[18];
  p.W2h  = (const float*)d_in[19];
  p.b2h  = (const float*)d_in[20];
  p.g2h  = (const float*)d_in[21];
  p.be2h = (const float*)d_in[22];
  p.Wo1  = (const float*)d_in[23];
  p.bo1  = (const float*)d_in[24];
  p.Wa   = (const float*)d_in[25];
  p.ba   = (const float*)d_in[26];
  p.Wm   = (const float*)d_in[27];
  p.bm   = (const float*)d_in[28];

  p.Ybf     = (unsigned short*)wsb;                                  // 40,550,400 B
  p.stats1  = (float*)(wsb + 40550400);                              // 4x256 f32
  p.stats2  = p.stats1 + 256;
  p.statsh1 = p.stats2 + 256;
  p.statsh2 = p.statsh1 + 256;
  p.scaleg  = (float*)(wsb + 40550400 + 4096);                       // ROWS f32
  p.scaleh  = p.scaleg + ROWS;                                       // HROWS f32
  p.y1h     = p.scaleh + HROWS;                                      // 800*128 f32
  p.y2h     = p.y1h + HROWS * 128;
  p.WtG     = (unsigned short*)(p.y2h + HROWS * 128);                // 2*16384 bf16
  p.partials = (float*)(p.WtG + 2 * 16384);                          // 512*256 f32
  p.cnt     = (unsigned*)(p.partials + (size_t)GEMMB * 256);         // 4 u32
  p.out     = (float*)d_out;

  k_prepW<<<256, 256, 0, stream>>>(p);
  k_gemm0W<<<GEMMB, 256, 0, stream>>>(p);
  k_gemm1W<<<GEMMB, 256, 0, stream>>>(p);
  k_h1W<<<400, 256, 0, stream>>>(p);
  k_h2W<<<400, 256, 0, stream>>>(p);
  k_finW<<<800, 256, 0, stream>>>(p);
}

// Round 13
// 291.877 us; speedup vs baseline: 2.1404x; 1.6556x over previous
//
#include <hip/hip_runtime.h>

// Problem constants: B=16,N=100,E=9900,M=50,F=64,H=128,K=20,D=2,T=8,S=8
#define BB 16
#define NN 100
#define EE 9900
#define MM 50
#define FF 64
#define KK 20
#define DD 2
#define ROWS (BB*EE)      // 158400 edge rows
#define HROWS (BB*MM)     // 800 hyper rows
#define BN_CNT (BB*NN)    // 1600
#define NTILE (ROWS/64)   // 2475 tiles of 64 rows
#define GEMMB 512         // gemm grid (R10-proven: 2 blocks/CU, no spill, no fences)
#define EPSF 1e-5f
#define XPITCH 136

typedef __attribute__((ext_vector_type(8))) short bf16x8;
typedef __attribute__((ext_vector_type(4))) float f32x4;

__device__ __forceinline__ float lrelu(float x) { return (x >= 0.f) ? x : 0.01f * x; }

__device__ __forceinline__ unsigned short f2bf(float x) {
  unsigned u = __float_as_uint(x);
  return (unsigned short)((u + 0x7fffu + ((u >> 16) & 1u)) >> 16);
}
__device__ __forceinline__ unsigned pk2(float a, float b) {
  return (unsigned)f2bf(a) | ((unsigned)f2bf(b) << 16);
}
__device__ __forceinline__ float bf2f(unsigned short u) {
  return __uint_as_float(((unsigned)u) << 16);
}

// ---------------- Threefry-2x32 (bit-exact vs JAX, partitionable XOR mode) -----------
__device__ __forceinline__ void tf2x32(unsigned k0, unsigned k1,
                                       unsigned x0, unsigned x1,
                                       unsigned& o0, unsigned& o1) {
  unsigned ks2 = k0 ^ k1 ^ 0x1BD11BDAu;
  x0 += k0; x1 += k1;
#define TFR(r) { x0 += x1; x1 = (x1 << r) | (x1 >> (32 - r)); x1 ^= x0; }
  TFR(13) TFR(15) TFR(26) TFR(6)   x0 += k1;  x1 += ks2 + 1u;
  TFR(17) TFR(29) TFR(16) TFR(24)  x0 += ks2; x1 += k0 + 2u;
  TFR(13) TFR(15) TFR(26) TFR(6)   x0 += k0;  x1 += k1 + 3u;
  TFR(17) TFR(29) TFR(16) TFR(24)  x0 += k1;  x1 += ks2 + 4u;
  TFR(13) TFR(15) TFR(26) TFR(6)   x0 += ks2; x1 += k0 + 5u;
#undef TFR
  o0 = x0; o1 = x1;
}

__device__ __forceinline__ float bits_to_normal(unsigned bits) {
  float f = __uint_as_float((bits >> 9) | 0x3f800000u) - 1.0f;  // [0,1)
  const float lo = -0.99999994f;                                 // nextafter(-1,0)
  float x = fmaxf(lo, fmaf(f, 2.0f, lo));
  float w = -log1pf(-x * x);
  float p;
  if (w < 5.0f) {
    w = w - 2.5f;
    p = 2.81022636e-08f;
    p = fmaf(p, w, 3.43273939e-07f);
    p = fmaf(p, w, -3.5233877e-06f);
    p = fmaf(p, w, -4.39150654e-06f);
    p = fmaf(p, w, 0.00021858087f);
    p = fmaf(p, w, -0.00125372503f);
    p = fmaf(p, w, -0.00417768164f);
    p = fmaf(p, w, 0.246640727f);
    p = fmaf(p, w, 1.50140941f);
  } else {
    w = sqrtf(w) - 3.0f;
    p = -0.000200214257f;
    p = fmaf(p, w, 0.000100950558f);
    p = fmaf(p, w, 0.00134934322f);
    p = fmaf(p, w, -0.00367342844f);
    p = fmaf(p, w, 0.00573950773f);
    p = fmaf(p, w, -0.0076224613f);
    p = fmaf(p, w, 0.00943887047f);
    p = fmaf(p, w, 1.00167406f);
    p = fmaf(p, w, 2.83297682f);
  }
  return 1.41421356237f * (p * x);
}

struct SmemGemm {
  unsigned short Xt[64 * XPITCH];
  float aColP[132], bColP[132];
  float bsum[128], bssq[128];
};

struct Params {
  const float *data, *rtg, *rth, *I_HG, *v;
  const float *W1g, *b1g, *g1g, *be1g, *W2g, *b2g, *g2g, *be2g;
  const float *W1h, *b1h, *g1h, *be1h, *W2h, *b2h, *g2h, *be2h;
  const float *Wo1, *bo1, *Wa, *ba, *Wm, *bm;
  unsigned short *Ybf, *WtG;
  float *stats1, *stats2, *statsh1, *statsh2, *scaleg, *scaleh;
  float *y1h, *y2h, *partials, *partial2;
  float *out;
};

// ---------------- prep: scales + W->bf16 transpose ----------------
__global__ __launch_bounds__(256) void k_prepW(Params p) {
  const int bid = blockIdx.x, tid = threadIdx.x;
  for (int i = bid * 256 + tid; i < ROWS + HROWS; i += 256 * 256) {
    if (i < ROWS) {
      float4 r = ((const float4*)p.rtg)[i];
      p.scaleg[i] = (r.x + r.y + r.z + r.w) * 0.25f;
    } else {
      float4 r = ((const float4*)p.rth)[i - ROWS];
      p.scaleh[i - ROWS] = (r.x + r.y + r.z + r.w) * 0.25f;
    }
  }
  {
    int i = bid * 256 + tid;
    if (i < 32768) {
      int w = i >> 14, rem = i & 16383;
      int c = rem & 127, k = rem >> 7;
      const float* W = w ? p.W2g : p.W1g;
      p.WtG[w * 16384 + c * 128 + k] = f2bf(W[k * 128 + c]);
    }
  }
}

// ---------------- edge GEMM (grid-stride pipelined; per-block partials, NO fences) ----
template <int MODE>
__device__ __forceinline__ void edge_gemm_phase(
    const Params& p, SmemGemm& sg, int bid, int nblk, int tid,
    const unsigned short* WtG, const unsigned short* Yin, unsigned short* Yout,
    const float* bias, const float* gmm, const float* beta,
    const float* stats_in) {
  const int lane = tid & 63, wid = tid >> 6;
  const int l15 = lane & 15, lq = lane >> 4;
  const int cb = wid * 32;
  const int rsi = tid >> 2, q = tid & 3, k0 = q * 32;

  if (tid < 128) {
    sg.bsum[tid] = 0.f; sg.bssq[tid] = 0.f;
    if (MODE == 1) {
      float s = stats_in[tid], ss = stats_in[128 + tid];
      float mu = s * (1.f / ROWS);
      float var = fmaxf(ss * (1.f / ROWS) - mu * mu, 0.f);
      float rs = 1.f / sqrtf(var + EPSF);
      float a = rs * gmm[tid];
      int pi = tid + (tid >> 5);
      sg.aColP[pi] = a; sg.bColP[pi] = beta[tid] - mu * a;
    }
  }

  const unsigned short* WA = WtG + (cb + l15) * 128 + lq * 8;
  bf16x8 a0[4], a1[4];
#pragma unroll
  for (int kc = 0; kc < 4; ++kc) {
    a0[kc] = *(const bf16x8*)(WA + kc * 32);
    a1[kc] = *(const bf16x8*)(WA + 16 * 128 + kc * 32);
  }
  float4 bi0 = *(const float4*)&bias[cb + lq * 4];
  float4 bi1 = *(const float4*)&bias[cb + 16 + lq * 4];
  f32x4 bv0 = {bi0.x, bi0.y, bi0.z, bi0.w};
  f32x4 bv1 = {bi1.x, bi1.y, bi1.z, bi1.w};
  f32x4 s0 = {0.f,0.f,0.f,0.f}, ss0 = {0.f,0.f,0.f,0.f};
  f32x4 s1 = {0.f,0.f,0.f,0.f}, ss1 = {0.f,0.f,0.f,0.f};

  float4 ra[4], rb[4];
  uint4  rw[4];

  auto LOAD = [&](int tile) {
    if (MODE == 0) {
      int g = tile * 64 + rsi;
      int b = g / EE; int e = g - b * EE;
      int i = e / 99; int jj = e - i * 99; int j = jj + ((jj >= i) ? 1 : 0);
      int vsrc = (q < 2) ? ((b * NN + i) * FF + q * 32)
                         : ((b * NN + j) * FF + (q - 2) * 32);
#pragma unroll
      for (int i2 = 0; i2 < 4; ++i2) {
        ra[i2] = *(const float4*)&p.v[vsrc + i2 * 8];
        rb[i2] = *(const float4*)&p.v[vsrc + i2 * 8 + 4];
      }
    } else {
      const unsigned short* src = Yin + (size_t)(tile * 64 + rsi) * 128 + k0;
#pragma unroll
      for (int i2 = 0; i2 < 4; ++i2) rw[i2] = *(const uint4*)&src[i2 * 8];
    }
  };
  auto WRITE = [&]() {
    if (MODE == 0) {
#pragma unroll
      for (int i2 = 0; i2 < 4; ++i2) {
        uint4 pk;
        pk.x = pk2(ra[i2].x, ra[i2].y); pk.y = pk2(ra[i2].z, ra[i2].w);
        pk.z = pk2(rb[i2].x, rb[i2].y); pk.w = pk2(rb[i2].z, rb[i2].w);
        *(uint4*)&sg.Xt[rsi * XPITCH + k0 + i2 * 8] = pk;
      }
    } else {
#pragma unroll
      for (int i2 = 0; i2 < 4; ++i2) {
        unsigned rr[4] = {rw[i2].x, rw[i2].y, rw[i2].z, rw[i2].w};
        unsigned ow[4];
#pragma unroll
        for (int u = 0; u < 4; ++u) {
          int k = k0 + i2 * 8 + u * 2;
          int p1 = k + (k >> 5);
          float xl = __uint_as_float(rr[u] << 16);
          float xh = __uint_as_float(rr[u] & 0xffff0000u);
          xl = lrelu(fmaf(xl, sg.aColP[p1], sg.bColP[p1]));
          xh = lrelu(fmaf(xh, sg.aColP[p1 + 1], sg.bColP[p1 + 1]));
          ow[u] = pk2(xl, xh);
        }
        uint4 pk; pk.x = ow[0]; pk.y = ow[1]; pk.z = ow[2]; pk.w = ow[3];
        *(uint4*)&sg.Xt[rsi * XPITCH + k0 + i2 * 8] = pk;
      }
    }
  };

  if (MODE == 1) __syncthreads();

  LOAD(bid);
  for (int t = bid; t < NTILE; t += nblk) {
    if (t != bid) __syncthreads();
    WRITE();
    if (t + nblk < NTILE) LOAD(t + nblk);
    __syncthreads();

    f32x4 acc[2][4];
#pragma unroll
    for (int a = 0; a < 2; ++a)
#pragma unroll
      for (int b2 = 0; b2 < 4; ++b2) acc[a][b2] = (f32x4){0.f, 0.f, 0.f, 0.f};
    const unsigned short* Bb = &sg.Xt[l15 * XPITCH + lq * 8];
#pragma unroll
    for (int kc = 0; kc < 4; ++kc) {
      int ko = kc * 32;
#pragma unroll
      for (int rbi = 0; rbi < 4; ++rbi) {
        bf16x8 bfr = *(const bf16x8*)(Bb + rbi * 16 * XPITCH + ko);
        acc[0][rbi] = __builtin_amdgcn_mfma_f32_16x16x32_bf16(a0[kc], bfr, acc[0][rbi], 0, 0, 0);
        acc[1][rbi] = __builtin_amdgcn_mfma_f32_16x16x32_bf16(a1[kc], bfr, acc[1][rbi], 0, 0, 0);
      }
    }

    int r0 = t * 64;
#pragma unroll
    for (int rbi = 0; rbi < 4; ++rbi) {
      size_t r = (size_t)(r0 + rbi * 16 + l15);
      f32x4 y0 = acc[0][rbi] + bv0;
      f32x4 y1 = acc[1][rbi] + bv1;
      uint2 w0; w0.x = pk2(y0.x, y0.y); w0.y = pk2(y0.z, y0.w);
      uint2 w1; w1.x = pk2(y1.x, y1.y); w1.y = pk2(y1.z, y1.w);
      *(uint2*)&Yout[r * 128 + cb + lq * 4] = w0;
      *(uint2*)&Yout[r * 128 + cb + 16 + lq * 4] = w1;
      s0 += y0; ss0 += y0 * y0;
      s1 += y1; ss1 += y1 * y1;
    }
  }

#pragma unroll
  for (int u = 0; u < 4; ++u) {
    atomicAdd(&sg.bsum[cb + lq * 4 + u], s0[u]);
    atomicAdd(&sg.bssq[cb + lq * 4 + u], ss0[u]);
    atomicAdd(&sg.bsum[cb + 16 + lq * 4 + u], s1[u]);
    atomicAdd(&sg.bssq[cb + 16 + lq * 4 + u], ss1[u]);
  }
  __syncthreads();
  if (tid < 128) {
    p.partials[(size_t)bid * 256 + tid] = sg.bsum[tid];
    p.partials[(size_t)bid * 256 + 128 + tid] = sg.bssq[tid];
  }
}

__global__ __launch_bounds__(256, 2) void k_gemm0W(Params p) {
  __shared__ __align__(16) SmemGemm sg;
  edge_gemm_phase<0>(p, sg, blockIdx.x, GEMMB, threadIdx.x, p.WtG, nullptr,
                     p.Ybf, p.b1g, nullptr, nullptr, nullptr);
}
__global__ __launch_bounds__(256, 2) void k_gemm1W(Params p) {
  __shared__ __align__(16) SmemGemm sg;
  edge_gemm_phase<1>(p, sg, blockIdx.x, GEMMB, threadIdx.x, p.WtG + 16384,
                     p.Ybf, p.Ybf, p.b2g, p.g1g, p.be1g, p.stats1);
}

// ---------------- stats reductions (kernel boundary = the fence; each ~3-5us) --------
__global__ __launch_bounds__(256) void k_redAW(const float* __restrict__ partials,
                                               float* __restrict__ partial2) {
  int bid = blockIdx.x, tid = threadIdx.x;   // 32 blocks
  float s = 0.f;
  for (int r = bid; r < GEMMB; r += 32) s += partials[(size_t)r * 256 + tid];
  partial2[bid * 256 + tid] = s;
}
__global__ __launch_bounds__(256) void k_redBW(const float* __restrict__ partial2,
                                               float* __restrict__ stats) {
  int tid = threadIdx.x;
  float s = 0.f;
#pragma unroll
  for (int r = 0; r < 32; ++r) s += partial2[r * 256 + tid];
  stats[tid] = s;
}

// ---------------- h1 / h2 (no fused stats; cs kernel is the fence) ----------------
__global__ __launch_bounds__(256) void k_h1W(Params p) {
  __shared__ float prerow[2][FF];
  const int bid = blockIdx.x, tid = threadIdx.x;
  const int sub = tid >> 7, ht = tid & 127;
  const int bm = bid * 2 + sub;                 // grid 400 -> bm < 800 always
  const int b = bm / MM, m = bm - b * MM;
  if (ht < FF) {
    float s = 0.f;
    for (int n = 0; n < NN; ++n)
      s = fmaf(p.I_HG[(b * NN + n) * MM + m], p.v[(b * NN + n) * FF + ht], s);
    prerow[sub][ht] = s;
  }
  __syncthreads();
  float y = p.b1h[ht];
  for (int f = 0; f < FF; ++f) y = fmaf(prerow[sub][f], p.W1h[f * 128 + ht], y);
  p.y1h[bm * 128 + ht] = y;
}

__global__ __launch_bounds__(256) void k_csW(const float* __restrict__ X,
                                             float* __restrict__ stats) {
  int c = blockIdx.x * 4 + (threadIdx.x >> 6), rt = threadIdx.x & 63;  // 32 blocks
  float s = 0.f, ss = 0.f;
  for (int r = rt; r < HROWS; r += 64) {
    float x = X[(size_t)r * 128 + c];
    s += x; ss += x * x;
  }
  for (int off = 32; off; off >>= 1) {
    s += __shfl_down(s, off, 64);
    ss += __shfl_down(ss, off, 64);
  }
  if (rt == 0) { stats[c] = s; stats[128 + c] = ss; }
}

__global__ __launch_bounds__(256) void k_h2W(Params p) {
  __shared__ float trow[2][128];
  const int bid = blockIdx.x, tid = threadIdx.x;
  const int sub = tid >> 7, ht = tid & 127;
  const int bm = bid * 2 + sub;
  float s = p.statsh1[ht], ss = p.statsh1[128 + ht];
  float mu = s * (1.f / HROWS);
  float var = fmaxf(ss * (1.f / HROWS) - mu * mu, 0.f);
  float rs = 1.f / sqrtf(var + EPSF);
  float a = rs * p.g1h[ht]; float bc = p.be1h[ht] - mu * a;
  trow[sub][ht] = lrelu(p.y1h[bm * 128 + ht] * a + bc);
  __syncthreads();
  float y = p.b2h[ht];
  for (int f = 0; f < 128; ++f) y = fmaf(trow[sub][f], p.W2h[f * 128 + ht], y);
  p.y2h[bm * 128 + ht] = y;
}

// ---------------- fused tail: recv + h3 + ve + out (one block-half per bn) -----------
struct SmemFin {
  float cat[2][256];            // [0:128)=hidden_g, [128:256)=hidden_hg
  float vres[2][128];
  float lgs[2][KK], mrow[2][KK * DD], alsh[2][KK], vcore[2][DD];
  float nz[2][8][2], ins[2][8][2];
};

__global__ __launch_bounds__(256) void k_finW(Params p) {
  __shared__ __align__(16) SmemFin sm;
  const int tid = threadIdx.x;
  const int sub = tid >> 7, ht = tid & 127;
  const int bn = blockIdx.x * 2 + sub;          // grid 800 -> bn < 1600 always
  const int b = bn / NN, n = bn - b * NN;

  // noise (independent; consumed after the barrier below)
  if (ht < 16) {
    int s = ht >> 1, d = ht & 1;
    unsigned fk0, fk1;
    tf2x32(0u, 1234u, 0u, (unsigned)s, fk0, fk1);
    unsigned flat = (unsigned)(bn * 2 + d);
    unsigned o0, o1;
    tf2x32(fk0, fk1, 0u, flat, o0, o1);
    sm.nz[sub][s][d] = bits_to_normal(o0 ^ o1);
  }

  // recv -> cat[sub][0:128)
  {
    float s = p.stats2[ht], ss = p.stats2[128 + ht];
    float mu = s * (1.f / ROWS);
    float var = fmaxf(ss * (1.f / ROWS) - mu * mu, 0.f);
    float rs = 1.f / sqrtf(var + EPSF);
    float a = rs * p.g2g[ht]; float bc = p.be2g[ht] - mu * a;
    float sv = (ht >= 64) ? p.v[(b * NN + n) * FF + (ht - 64)] : 0.f;
    float acc = 0.f;
#pragma unroll 4
    for (int i = 0; i < NN; ++i) {
      if (i == n) continue;
      int e = i * 99 + ((n < i) ? n : n - 1);
      int row = b * EE + e;
      float y = bf2f(p.Ybf[(size_t)row * 128 + ht]);
      float msgv = lrelu(y * a + bc);
      float pre = (ht < 64) ? p.v[(b * NN + i) * FF + ht] : sv;
      acc += lrelu(fmaf(msgv, p.scaleg[row], pre));
    }
    sm.cat[sub][ht] = acc * 0.5f;
  }
  // h3 -> cat[sub][128:256)
  {
    float s = p.statsh2[ht], ss = p.statsh2[128 + ht];
    float mu = s * (1.f / HROWS);
    float var = fmaxf(ss * (1.f / HROWS) - mu * mu, 0.f);
    float rs = 1.f / sqrtf(var + EPSF);
    float a = rs * p.g2h[ht]; float bc = p.be2h[ht] - mu * a;
    float acc = 0.f;
    for (int m = 0; m < MM; ++m) {
      float x = lrelu(p.y2h[(b * MM + m) * 128 + ht] * a + bc);
      acc = fmaf(x * p.scaleh[b * MM + m], p.I_HG[(b * NN + n) * MM + m], acc);
    }
    sm.cat[sub][128 + ht] = acc * 0.5f;
  }
  __syncthreads();

  // ve: v = lrelu(cat @ Wo1 + bo1)
  float vv = p.bo1[ht];
  for (int k = 0; k < 256; ++k)
    vv = fmaf(sm.cat[sub][k], p.Wo1[k * 128 + ht], vv);
  sm.vres[sub][ht] = lrelu(vv);
  __syncthreads();
  if (ht < KK) {
    float s = p.ba[ht];
    for (int f = 0; f < 128; ++f) s = fmaf(sm.vres[sub][f], p.Wa[f * KK + ht], s);
    sm.lgs[sub][ht] = s;
  } else if (ht >= 64 && ht < 64 + KK * DD) {
    int c = ht - 64;
    float s = p.bm[c];
    for (int f = 0; f < 128; ++f) s = fmaf(sm.vres[sub][f], p.Wm[f * (KK * DD) + c], s);
    sm.mrow[sub][c] = s;
  }
  __syncthreads();
  if (ht < KK) {
    float mx = sm.lgs[sub][0];
    for (int k2 = 1; k2 < KK; ++k2) mx = fmaxf(mx, sm.lgs[sub][k2]);
    float se = 0.f;
    for (int k2 = 0; k2 < KK; ++k2) se += expf(sm.lgs[sub][k2] - mx);
    sm.alsh[sub][ht] = expf(sm.lgs[sub][ht] - mx) / se;
  }
  __syncthreads();
  if (ht < DD) {
    float s = 0.f;
    for (int k2 = 0; k2 < KK; ++k2)
      s = fmaf(sm.alsh[sub][k2], sm.mrow[sub][k2 * DD + ht], s);
    sm.vcore[sub][ht] = s;
  }
  __syncthreads();

  // out: preds / alphas / mus / sigmas (all operands in LDS)
  if (ht < 2) {
    int d = ht;
    float pp = p.data[bn * 16 + d];             // data[b,n,0,d]
    float core = sm.vcore[sub][d];
    for (int s = 0; s < 8; ++s) {
      sm.ins[sub][s][d] = pp;
      pp = (pp + core) + sm.nz[sub][s][d];
      p.out[(bn * 8 + s) * 2 + d] = pp;
    }
  }
  __syncthreads();
  for (int q = ht; q < 160; q += 128)
    p.out[25600 + bn * 160 + q] = sm.alsh[sub][q % KK];
  for (int q = ht; q < 320; q += 128) {
    int s = q / 40, kd = q - s * 40, d = kd & 1;
    p.out[281600 + bn * 320 + q] = sm.mrow[sub][kd] + sm.ins[sub][s][d];
  }
  for (int q = ht; q < 320; q += 128) p.out[793600 + bn * 320 + q] = 1.0f;
}

extern "C" void kernel_launch(void* const* d_in, const int* in_sizes, int n_in,
                              void* d_out, int out_size, void* d_ws, size_t ws_size,
                              hipStream_t stream) {
  char* wsb = (char*)d_ws;

  Params p;
  p.data = (const float*)d_in[0];
  p.rtg  = (const float*)d_in[3];
  p.rth  = (const float*)d_in[4];
  p.I_HG = (const float*)d_in[5];
  p.v    = (const float*)d_in[6];
  p.W1g  = (const float*)d_in[7];
  p.b1g  = (const float*)d_in[8];
  p.g1g  = (const float*)d_in[9];
  p.be1g = (const float*)d_in[10];
  p.W2g  = (const float*)d_in[11];
  p.b2g  = (const float*)d_in[12];
  p.g2g  = (const float*)d_in[13];
  p.be2g = (const float*)d_in[14];
  p.W1h  = (const float*)d_in[15];
  p.b1h  = (const float*)d_in[16];
  p.g1h  = (const float*)d_in[17];
  p.be1h = (const float*)d_in[18];
  p.W2h  = (const float*)d_in[19];
  p.b2h  = (const float*)d_in[20];
  p.g2h  = (const float*)d_in[21];
  p.be2h = (const float*)d_in[22];
  p.Wo1  = (const float*)d_in[23];
  p.bo1  = (const float*)d_in[24];
  p.Wa   = (const float*)d_in[25];
  p.ba   = (const float*)d_in[26];
  p.Wm   = (const float*)d_in[27];
  p.bm   = (const float*)d_in[28];

  p.Ybf     = (unsigned short*)wsb;                                  // 40,550,400 B
  p.stats1  = (float*)(wsb + 40550400);                              // 4x256 f32
  p.stats2  = p.stats1 + 256;
  p.statsh1 = p.stats2 + 256;
  p.statsh2 = p.statsh1 + 256;
  p.scaleg  = (float*)(wsb + 40550400 + 4096);                       // ROWS f32
  p.scaleh  = p.scaleg + ROWS;                                       // HROWS f32
  p.y1h     = p.scaleh + HROWS;                                      // 800*128 f32
  p.y2h     = p.y1h + HROWS * 128;
  p.WtG     = (unsigned short*)(p.y2h + HROWS * 128);                // 2*16384 bf16
  p.partials = (float*)(p.WtG + 2 * 16384);                          // 512*256 f32
  p.partial2 = p.partials + (size_t)GEMMB * 256;                     // 32*256 f32
  p.out     = (float*)d_out;

  k_prepW<<<256, 256, 0, stream>>>(p);
  k_gemm0W<<<GEMMB, 256, 0, stream>>>(p);
  k_redAW<<<32, 256, 0, stream>>>(p.partials, p.partial2);
  k_redBW<<<1, 256, 0, stream>>>(p.partial2, p.stats1);
  k_gemm1W<<<GEMMB, 256, 0, stream>>>(p);
  k_redAW<<<32, 256, 0, stream>>>(p.partials, p.partial2);
  k_redBW<<<1, 256, 0, stream>>>(p.partial2, p.stats2);
  k_h1W<<<400, 256, 0, stream>>>(p);
  k_csW<<<32, 256, 0, stream>>>(p.y1h, p.statsh1);
  k_h2W<<<400, 256, 0, stream>>>(p);
  k_csW<<<32, 256, 0, stream>>>(p.y2h, p.statsh2);
  k_finW<<<800, 256, 0, stream>>>(p);
}